// Round 3
// baseline (970.596 us; speedup 1.0000x reference)
//
#include <hip/hip_runtime.h>

// PiKVMoE fused forward, MI355X gfx950.
// out[n,f] = sum_e gate[n,e] * ( relu( sum_k x[n,k]*W[e,k,f] + b[e,f] ) + cached[e,f] )
// gate = softmax(x @ Wg + bg)
// N=8192 tokens, H=2048 hidden, E=8 experts. Compute-bound: 550 GFLOP.
// Strategy: bf16 MFMA (16x16x32), m97-structure 128x128 tile, expert loop in-block.

#define NT 8192
#define HD 2048
#define NE 8

typedef __attribute__((ext_vector_type(8))) short short8;
typedef __attribute__((ext_vector_type(4))) float f32x4;

// RTNE float -> bf16 bits
__device__ __forceinline__ unsigned int f2bf(float f) {
  unsigned int u = __float_as_uint(f);
  u += 0x7FFFu + ((u >> 16) & 1u);
  return u >> 16;
}

// ---------------- kernel 1: gate = softmax(x @ Wg + bg), f32 exact ----------------
__global__ void gate_kernel(const float* __restrict__ x, const float* __restrict__ Wg,
                            const float* __restrict__ bg, float* __restrict__ gate) {
  const int w = threadIdx.x >> 6, l = threadIdx.x & 63;
  const int n = blockIdx.x * 4 + w;
  const float4* x4 = (const float4*)(x + (size_t)n * HD);
  const float4* wg4 = (const float4*)Wg;  // Wg[h][e], 8 floats per h
  float acc[NE] = {0.f, 0.f, 0.f, 0.f, 0.f, 0.f, 0.f, 0.f};
  #pragma unroll
  for (int i = 0; i < HD / 256; ++i) {  // 8 float4 per lane
    const int h4 = l + 64 * i;
    const float4 xv = x4[h4];
    #pragma unroll
    for (int c = 0; c < 4; ++c) {
      const float xs = (c == 0) ? xv.x : (c == 1) ? xv.y : (c == 2) ? xv.z : xv.w;
      const float4 w0 = wg4[(h4 * 4 + c) * 2];
      const float4 w1 = wg4[(h4 * 4 + c) * 2 + 1];
      acc[0] += xs * w0.x; acc[1] += xs * w0.y; acc[2] += xs * w0.z; acc[3] += xs * w0.w;
      acc[4] += xs * w1.x; acc[5] += xs * w1.y; acc[6] += xs * w1.z; acc[7] += xs * w1.w;
    }
  }
  #pragma unroll
  for (int off = 32; off > 0; off >>= 1) {
    #pragma unroll
    for (int e = 0; e < NE; ++e) acc[e] += __shfl_xor(acc[e], off);
  }
  if (l == 0) {
    float lg[NE], m = -1e30f;
    #pragma unroll
    for (int e = 0; e < NE; ++e) { lg[e] = acc[e] + bg[e]; m = fmaxf(m, lg[e]); }
    float s = 0.f;
    #pragma unroll
    for (int e = 0; e < NE; ++e) { lg[e] = expf(lg[e] - m); s += lg[e]; }
    const float inv = 1.f / s;
    #pragma unroll
    for (int e = 0; e < NE; ++e) gate[(size_t)n * NE + e] = lg[e] * inv;
  }
}

// ---------------- kernel 2: x (f32) -> xb (bf16), 8 elems/thread ----------------
__global__ void xconv_kernel(const float* __restrict__ x, unsigned short* __restrict__ xb) {
  const size_t i = (size_t)blockIdx.x * 256 + threadIdx.x;
  const float4 a = ((const float4*)x)[i * 2];
  const float4 c = ((const float4*)x)[i * 2 + 1];
  uint4 o;
  o.x = f2bf(a.x) | (f2bf(a.y) << 16);
  o.y = f2bf(a.z) | (f2bf(a.w) << 16);
  o.z = f2bf(c.x) | (f2bf(c.y) << 16);
  o.w = f2bf(c.z) | (f2bf(c.w) << 16);
  ((uint4*)xb)[i] = o;
}

// ---------------- kernel 3: Wt[e][f][k] = bf16(W[e][k][f]) (tiled transpose) ----------------
__global__ void wtrans_kernel(const float* __restrict__ W, unsigned short* __restrict__ Wt) {
  __shared__ unsigned short tl[64][65];  // +1 pad breaks bank aliasing on transposed read
  const int e = blockIdx.z, kb = blockIdx.y * 64, fb = blockIdx.x * 64;
  const int c = threadIdx.x & 63, rq = threadIdx.x >> 6;
  const float* Wp = W + (size_t)e * HD * HD;
  #pragma unroll
  for (int i = 0; i < 16; ++i) {
    const int r = rq * 16 + i;
    tl[r][c] = (unsigned short)f2bf(Wp[(size_t)(kb + r) * HD + fb + c]);
  }
  __syncthreads();
  unsigned short* Wtp = Wt + (size_t)e * HD * HD;
  #pragma unroll
  for (int i = 0; i < 16; ++i) {
    const int fr = rq * 16 + i;
    Wtp[(size_t)(fb + fr) * HD + kb + c] = tl[c][fr];
  }
}

// ---------------- kernel 4: fused expert GEMMs + gated accumulation ----------------
// 128x128 tile, BK=32, 4 waves (2x2), each wave 64x64 = 4x4 frags of 16x16x32 bf16 MFMA.
// LDS tiles As/Bs: [128 rows][32 bf16] with chunk-XOR swizzle: the 16B chunk holding
// logical k-chunk g of row r sits at physical chunk g ^ ((r>>1)&3).
// Staging is linear global_load_lds (wave-uniform LDS dest + lane*16); the swizzle is
// realized by permuting the per-lane GLOBAL source address (both-sides rule, m173/m231).
__global__ __launch_bounds__(256, 2) void moe_main(
    const unsigned short* __restrict__ xb, const unsigned short* __restrict__ wt,
    const float* __restrict__ b, const float* __restrict__ cached,
    const float* __restrict__ gate, float* __restrict__ out) {
  __shared__ unsigned short lds[8192];  // As: [0,4096) ushorts, Bs: [4096,8192)
  auto lds3 = (__attribute__((address_space(3))) unsigned short*)lds;

  const int t = threadIdx.x, w = t >> 6, l = t & 63;
  const int wm = w >> 1, wn = w & 1;
  const int n0 = blockIdx.y * 128, f0 = blockIdx.x * 128;

  // staging: instr (w,j) covers LDS bytes [(w*2+j)*1024, +1024); lane l writes 16B at +l*16
  // -> row = (w*2+j)*16 + (l>>2), physical chunk = l&3, logical chunk = (l&3)^((l>>3)&3)
  const int sr = l >> 2;
  const int chl = (l & 3) ^ ((l >> 3) & 3);
  const unsigned short* aSrc = xb + (size_t)n0 * HD + chl * 8;

  // frag reads: lane l, frag row fm=l&15, k-group g=l>>4; physical chunk = g ^ ((m>>1)&3)
  const int fm = l & 15;
  const int qr = l >> 4;
  const int rg = qr ^ ((l >> 1) & 3);  // ((mi*16+fm)>>1)&3 == (fm>>1)&3 == (l>>1)&3
  const unsigned short* aRd = &lds[(size_t)(wm * 64 + fm) * 32 + rg * 8];
  const unsigned short* bRd = &lds[4096 + (size_t)(wn * 64 + fm) * 32 + rg * 8];

  f32x4 oacc[4][4] = {};

  for (int e = 0; e < NE; ++e) {
    f32x4 acc[4][4] = {};
    const unsigned short* bSrc = wt + (size_t)e * HD * HD + (size_t)f0 * HD + chl * 8;

    for (int kt = 0; kt < HD / 32; ++kt) {
      __syncthreads();  // prior iter's ds_reads done before overwrite
      #pragma unroll
      for (int j = 0; j < 2; ++j) {
        const int rw = (w * 2 + j) * 16 + sr;
        __builtin_amdgcn_global_load_lds(
            (const __attribute__((address_space(1))) void*)(aSrc + (size_t)rw * HD + kt * 32),
            (__attribute__((address_space(3))) void*)(lds3 + (w * 2 + j) * 512), 16, 0, 0);
        __builtin_amdgcn_global_load_lds(
            (const __attribute__((address_space(1))) void*)(bSrc + (size_t)rw * HD + kt * 32),
            (__attribute__((address_space(3))) void*)(lds3 + 4096 + (w * 2 + j) * 512), 16, 0, 0);
      }
      __syncthreads();  // drains vmcnt -> staged data visible

      short8 av[4], bv[4];
      #pragma unroll
      for (int mi = 0; mi < 4; ++mi) av[mi] = *(const short8*)(aRd + mi * 512);
      #pragma unroll
      for (int ni = 0; ni < 4; ++ni) bv[ni] = *(const short8*)(bRd + ni * 512);
      #pragma unroll
      for (int mi = 0; mi < 4; ++mi)
        #pragma unroll
        for (int ni = 0; ni < 4; ++ni)
          acc[mi][ni] = __builtin_amdgcn_mfma_f32_16x16x32_bf16(av[mi], bv[ni], acc[mi][ni], 0, 0, 0);
    }

    // epilogue for expert e: oacc += gate * (relu(acc + b) + cached)
    float gv[16];
    #pragma unroll
    for (int mi = 0; mi < 4; ++mi)
      #pragma unroll
      for (int j2 = 0; j2 < 4; ++j2)
        gv[mi * 4 + j2] = gate[(size_t)(n0 + wm * 64 + mi * 16 + qr * 4 + j2) * NE + e];
    #pragma unroll
    for (int ni = 0; ni < 4; ++ni) {
      const int f = f0 + wn * 64 + ni * 16 + fm;
      const float bias = b[(size_t)e * HD + f];
      const float cv = cached[(size_t)e * HD + f];
      #pragma unroll
      for (int mi = 0; mi < 4; ++mi)
        #pragma unroll
        for (int j2 = 0; j2 < 4; ++j2) {
          float v = acc[mi][ni][j2] + bias;
          v = fmaxf(v, 0.f) + cv;
          oacc[mi][ni][j2] += gv[mi * 4 + j2] * v;
        }
    }
  }

  // store: C/D frag layout col=l&15, row=(l>>4)*4+j (m89-verified)
  #pragma unroll
  for (int mi = 0; mi < 4; ++mi)
    #pragma unroll
    for (int j2 = 0; j2 < 4; ++j2) {
      const size_t n = n0 + wm * 64 + mi * 16 + qr * 4 + j2;
      float* orow = out + n * HD + f0 + wn * 64 + fm;
      #pragma unroll
      for (int ni = 0; ni < 4; ++ni) orow[ni * 16] = oacc[mi][ni][j2];
    }
}

extern "C" void kernel_launch(void* const* d_in, const int* in_sizes, int n_in,
                              void* d_out, int out_size, void* d_ws, size_t ws_size,
                              hipStream_t stream) {
  const float* x      = (const float*)d_in[0];
  const float* W      = (const float*)d_in[1];
  const float* b      = (const float*)d_in[2];
  const float* Wg     = (const float*)d_in[3];
  const float* bg     = (const float*)d_in[4];
  const float* cached = (const float*)d_in[5];
  float* out = (float*)d_out;

  // ws layout: gate[N*E f32] | xb[N*H bf16] | wt[E*H*H bf16]  (~96.3 MB)
  char* ws = (char*)d_ws;
  float* gate = (float*)ws;
  unsigned short* xbuf = (unsigned short*)(ws + (size_t)NT * NE * 4);
  unsigned short* wtb  = (unsigned short*)(ws + (size_t)NT * NE * 4 + (size_t)NT * HD * 2);

  gate_kernel<<<NT / 4, 256, 0, stream>>>(x, Wg, bg, gate);
  xconv_kernel<<<(NT * HD / 8) / 256, 256, 0, stream>>>(x, xbuf);
  wtrans_kernel<<<dim3(HD / 64, HD / 64, NE), 256, 0, stream>>>(W, wtb);
  moe_main<<<dim3(HD / 128, NT / 128), 256, 0, stream>>>(xbuf, wtb, b, cached, gate, out);
}

// Round 5
// 946.700 us; speedup vs baseline: 1.0252x; 1.0252x over previous
//
#include <hip/hip_runtime.h>

// PiKVMoE fused forward, MI355X gfx950.
// out[n,f] = sum_e gate[n,e] * ( relu( sum_k x[n,k]*W[e,k,f] + b[e,f] ) + cached[e,f] )
// gate = softmax(x @ Wg + bg)
// N=8192, H=2048, E=8. 550 GFLOP, compute-bound.
// R4: counted-vmcnt deep pipeline (T3+T4), ring-3 LDS (144KB), BM128xBN256 BK64,
//     8 waves 64x64/wave, per-phase barriers + setprio (T5), XCD f-panel swizzle (T1).

#define NT 8192
#define HD 2048
#define NE 8

typedef __attribute__((ext_vector_type(8))) short short8;
typedef __attribute__((ext_vector_type(4))) float f32x4;

__device__ __forceinline__ unsigned int f2bf(float f) {
  unsigned int u = __float_as_uint(f);
  u += 0x7FFFu + ((u >> 16) & 1u);
  return u >> 16;
}

// ---------------- kernel 1: gate softmax (f32 exact) + x->bf16 conversion fused ----------------
__global__ void gate_kernel(const float* __restrict__ x, const float* __restrict__ Wg,
                            const float* __restrict__ bg, float* __restrict__ gate,
                            unsigned short* __restrict__ xb) {
  const int w = threadIdx.x >> 6, l = threadIdx.x & 63;
  const int n = blockIdx.x * 4 + w;
  const float4* x4 = (const float4*)(x + (size_t)n * HD);
  uint2* xbrow = (uint2*)(xb + (size_t)n * HD);
  const float4* wg4 = (const float4*)Wg;  // Wg[h][e], 8 floats per h
  float acc[NE] = {0.f, 0.f, 0.f, 0.f, 0.f, 0.f, 0.f, 0.f};
  #pragma unroll
  for (int i = 0; i < HD / 256; ++i) {  // 8 float4 per lane
    const int h4 = l + 64 * i;
    const float4 xv = x4[h4];
    uint2 o;
    o.x = f2bf(xv.x) | (f2bf(xv.y) << 16);
    o.y = f2bf(xv.z) | (f2bf(xv.w) << 16);
    xbrow[h4] = o;  // fused x->bf16 store (coalesced: lanes 8B apart)
    #pragma unroll
    for (int c = 0; c < 4; ++c) {
      const float xs = (c == 0) ? xv.x : (c == 1) ? xv.y : (c == 2) ? xv.z : xv.w;
      const float4 w0 = wg4[(h4 * 4 + c) * 2];
      const float4 w1 = wg4[(h4 * 4 + c) * 2 + 1];
      acc[0] += xs * w0.x; acc[1] += xs * w0.y; acc[2] += xs * w0.z; acc[3] += xs * w0.w;
      acc[4] += xs * w1.x; acc[5] += xs * w1.y; acc[6] += xs * w1.z; acc[7] += xs * w1.w;
    }
  }
  #pragma unroll
  for (int off = 32; off > 0; off >>= 1) {
    #pragma unroll
    for (int e = 0; e < NE; ++e) acc[e] += __shfl_xor(acc[e], off);
  }
  if (l == 0) {
    float lg[NE], m = -1e30f;
    #pragma unroll
    for (int e = 0; e < NE; ++e) { lg[e] = acc[e] + bg[e]; m = fmaxf(m, lg[e]); }
    float s = 0.f;
    #pragma unroll
    for (int e = 0; e < NE; ++e) { lg[e] = expf(lg[e] - m); s += lg[e]; }
    const float inv = 1.f / s;
    #pragma unroll
    for (int e = 0; e < NE; ++e) gate[(size_t)n * NE + e] = lg[e] * inv;
  }
}

// ---------------- kernel 2: Wt[e][f][k] = bf16(W[e][k][f]) (tiled transpose) ----------------
__global__ void wtrans_kernel(const float* __restrict__ W, unsigned short* __restrict__ Wt) {
  __shared__ unsigned short tl[64][65];
  const int e = blockIdx.z, kb = blockIdx.y * 64, fb = blockIdx.x * 64;
  const int c = threadIdx.x & 63, rq = threadIdx.x >> 6;
  const float* Wp = W + (size_t)e * HD * HD;
  #pragma unroll
  for (int i = 0; i < 16; ++i) {
    const int r = rq * 16 + i;
    tl[r][c] = (unsigned short)f2bf(Wp[(size_t)(kb + r) * HD + fb + c]);
  }
  __syncthreads();
  unsigned short* Wtp = Wt + (size_t)e * HD * HD;
  #pragma unroll
  for (int i = 0; i < 16; ++i) {
    const int fr = rq * 16 + i;
    Wtp[(size_t)(fb + fr) * HD + kb + c] = tl[c][fr];
  }
}

// ---------------- kernel 3: fused expert GEMMs, deep-pipelined ----------------
// Tile: BM=128 (tokens) x BN=256 (f), BK=64. 8 waves in 2(m)x4(n) grid, 64x64 out/wave.
// LDS: ring of 3 tile-buffers, each 48KB (A 16KB + B 32KB), 144KB total (dynamic).
// Tile T = e*32 + kt (256 tiles). While computing T, tile T+2 is staged (6 gload_lds/wave);
// entry wait: s_waitcnt vmcnt(6) (T+1's 6 loads stay in flight) -- never drains to 0
// except at the last tile. Swizzle: 128B rows, 8x16B chunks, phys = logical ^ (row&7);
// staging keeps LDS dest linear and pre-swizzles the GLOBAL source (both-sides rule).
__global__ __launch_bounds__(512, 2) void moe_main(
    const unsigned short* __restrict__ xb, const unsigned short* __restrict__ wt,
    const float* __restrict__ b, const float* __restrict__ cached,
    const float* __restrict__ gate, float* __restrict__ out) {
  extern __shared__ unsigned short lds[];
  auto lds3 = (__attribute__((address_space(3))) unsigned short*)lds;

  const int t = threadIdx.x, w = t >> 6, l = t & 63;
  const int wm = w >> 2, wn = w & 3;
  // XCD swizzle: hardware assigns XCD = blockIdx % 8 (round-robin); make f-panel = bid&7
  // so each XCD streams a single 8MB wt panel (L2/L3 locality).
  const int n0 = (blockIdx.x >> 3) * 128;
  const int f0 = (blockIdx.x & 7) * 256;

  // ---- staging source addresses (pre-swizzled global, linear LDS dest) ----
  // each gload_lds covers 8 rows (1KB): lane l -> row +(l>>3), phys chunk (l&7).
  // logical chunk = (l&7) ^ (l>>3)  (rows 8-aligned).
  const int sr = l >> 3;
  const int cl = (l & 7) ^ sr;
  const unsigned short* aB0 = xb + (size_t)(n0 + (2 * w + 0) * 8 + sr) * HD + cl * 8;
  const unsigned short* aB1 = xb + (size_t)(n0 + (2 * w + 1) * 8 + sr) * HD + cl * 8;
  const unsigned short* bB0 = wt + (size_t)(f0 + (4 * w + 0) * 8 + sr) * HD + cl * 8;
  const unsigned short* bB1 = wt + (size_t)(f0 + (4 * w + 1) * 8 + sr) * HD + cl * 8;
  const unsigned short* bB2 = wt + (size_t)(f0 + (4 * w + 2) * 8 + sr) * HD + cl * 8;
  const unsigned short* bB3 = wt + (size_t)(f0 + (4 * w + 3) * 8 + sr) * HD + cl * 8;

  // ---- fragment read offsets (ushort units, within a tile buffer) ----
  const int fm = l & 15, qr = l >> 4;
  const int aOff = (wm * 64 + fm) * 64;          // + mi*1024 + chunk
  const int bOff = 8192 + (wn * 64 + fm) * 64;   // + ni*1024 + chunk
  const int ch0 = ((0 + qr) ^ (fm & 7)) * 8;     // kk=0 phys chunk
  const int ch1 = ((4 + qr) ^ (fm & 7)) * 8;     // kk=1 phys chunk

  #define GLD(src, dstoff) __builtin_amdgcn_global_load_lds( \
      (const __attribute__((address_space(1))) void*)(src),  \
      (__attribute__((address_space(3))) void*)(lds3 + (dstoff)), 16, 0, 0)

  // prologue: stage tiles 0 and 1 (6 loads each per wave)
  #pragma unroll
  for (int T0 = 0; T0 < 2; ++T0) {
    const size_t ko = (size_t)(T0 & 31) * 64;
    const size_t eo = ko;  // e=0 for T0 in {0,1}
    const int base = (T0 % 3) * 24576;
    GLD(aB0 + ko, base + (2 * w + 0) * 512);
    GLD(aB1 + ko, base + (2 * w + 1) * 512);
    GLD(bB0 + eo, base + 8192 + (4 * w + 0) * 512);
    GLD(bB1 + eo, base + 8192 + (4 * w + 1) * 512);
    GLD(bB2 + eo, base + 8192 + (4 * w + 2) * 512);
    GLD(bB3 + eo, base + 8192 + (4 * w + 3) * 512);
  }

  f32x4 oacc[4][4] = {};

  for (int e = 0; e < NE; ++e) {
    f32x4 acc[4][4] = {};
    for (int kt = 0; kt < 32; ++kt) {
      const int T = e * 32 + kt;
      // entry: my 6 loads for tile T landed (T+1's 6 may remain in flight)
      if (T == 255) { asm volatile("s_waitcnt vmcnt(0)" ::: "memory"); }
      else          { asm volatile("s_waitcnt vmcnt(6)" ::: "memory"); }
      __builtin_amdgcn_s_barrier();  // everyone's stages landed; buf[(T+2)%3] free

      const unsigned short* buf = lds + (T % 3) * 24576;
      const bool doStage = (T + 2) < 256;
      const int Ts = T + 2;
      const int sbase = (Ts % 3) * 24576;
      const size_t ko = (size_t)(Ts & 31) * 64;
      const size_t eo = (size_t)(Ts >> 5) * HD * HD + ko;

      #pragma unroll
      for (int ph = 0; ph < 4; ++ph) {
        // interleaved prefetch of tile T+2 (2,2,1,1 across phases)
        if (ph == 0 && doStage) {
          GLD(aB0 + ko, sbase + (2 * w + 0) * 512);
          GLD(aB1 + ko, sbase + (2 * w + 1) * 512);
        }
        if (ph == 1 && doStage) {
          GLD(bB0 + eo, sbase + 8192 + (4 * w + 0) * 512);
          GLD(bB1 + eo, sbase + 8192 + (4 * w + 1) * 512);
        }
        if (ph == 2 && doStage) { GLD(bB2 + eo, sbase + 8192 + (4 * w + 2) * 512); }
        if (ph == 3 && doStage) { GLD(bB3 + eo, sbase + 8192 + (4 * w + 3) * 512); }

        const int pm = ph >> 1, pn = ph & 1;
        short8 a0k0 = *(const short8*)(buf + aOff + (pm * 2 + 0) * 1024 + ch0);
        short8 a0k1 = *(const short8*)(buf + aOff + (pm * 2 + 0) * 1024 + ch1);
        short8 a1k0 = *(const short8*)(buf + aOff + (pm * 2 + 1) * 1024 + ch0);
        short8 a1k1 = *(const short8*)(buf + aOff + (pm * 2 + 1) * 1024 + ch1);
        short8 b0k0 = *(const short8*)(buf + bOff + (pn * 2 + 0) * 1024 + ch0);
        short8 b0k1 = *(const short8*)(buf + bOff + (pn * 2 + 0) * 1024 + ch1);
        short8 b1k0 = *(const short8*)(buf + bOff + (pn * 2 + 1) * 1024 + ch0);
        short8 b1k1 = *(const short8*)(buf + bOff + (pn * 2 + 1) * 1024 + ch1);

        __builtin_amdgcn_s_barrier();  // phase lockstep (m201 pattern)
        __builtin_amdgcn_s_setprio(1);
        acc[pm*2+0][pn*2+0] = __builtin_amdgcn_mfma_f32_16x16x32_bf16(a0k0, b0k0, acc[pm*2+0][pn*2+0], 0, 0, 0);
        acc[pm*2+0][pn*2+1] = __builtin_amdgcn_mfma_f32_16x16x32_bf16(a0k0, b1k0, acc[pm*2+0][pn*2+1], 0, 0, 0);
        acc[pm*2+1][pn*2+0] = __builtin_amdgcn_mfma_f32_16x16x32_bf16(a1k0, b0k0, acc[pm*2+1][pn*2+0], 0, 0, 0);
        acc[pm*2+1][pn*2+1] = __builtin_amdgcn_mfma_f32_16x16x32_bf16(a1k0, b1k0, acc[pm*2+1][pn*2+1], 0, 0, 0);
        acc[pm*2+0][pn*2+0] = __builtin_amdgcn_mfma_f32_16x16x32_bf16(a0k1, b0k1, acc[pm*2+0][pn*2+0], 0, 0, 0);
        acc[pm*2+0][pn*2+1] = __builtin_amdgcn_mfma_f32_16x16x32_bf16(a0k1, b1k1, acc[pm*2+0][pn*2+1], 0, 0, 0);
        acc[pm*2+1][pn*2+0] = __builtin_amdgcn_mfma_f32_16x16x32_bf16(a1k1, b0k1, acc[pm*2+1][pn*2+0], 0, 0, 0);
        acc[pm*2+1][pn*2+1] = __builtin_amdgcn_mfma_f32_16x16x32_bf16(a1k1, b1k1, acc[pm*2+1][pn*2+1], 0, 0, 0);
        __builtin_amdgcn_s_setprio(0);
        __builtin_amdgcn_s_barrier();
      }
    }

    // epilogue for expert e: oacc += gate * (relu(acc + b) + cached)
    float gv[16];
    #pragma unroll
    for (int mi = 0; mi < 4; ++mi)
      #pragma unroll
      for (int j2 = 0; j2 < 4; ++j2)
        gv[mi * 4 + j2] = gate[(size_t)(n0 + wm * 64 + mi * 16 + qr * 4 + j2) * NE + e];
    #pragma unroll
    for (int ni = 0; ni < 4; ++ni) {
      const int f = f0 + wn * 64 + ni * 16 + fm;
      const float bias = b[(size_t)e * HD + f];
      const float cv = cached[(size_t)e * HD + f];
      #pragma unroll
      for (int mi = 0; mi < 4; ++mi)
        #pragma unroll
        for (int j2 = 0; j2 < 4; ++j2) {
          float v = acc[mi][ni][j2] + bias;
          v = fmaxf(v, 0.f) + cv;
          oacc[mi][ni][j2] += gv[mi * 4 + j2] * v;
        }
    }
  }

  // store: C/D frag layout col=l&15, row=(l>>4)*4+j (m89-verified)
  #pragma unroll
  for (int mi = 0; mi < 4; ++mi)
    #pragma unroll
    for (int j2 = 0; j2 < 4; ++j2) {
      const size_t n = n0 + wm * 64 + mi * 16 + qr * 4 + j2;
      float* orow = out + n * HD + f0 + wn * 64 + fm;
      #pragma unroll
      for (int ni = 0; ni < 4; ++ni) orow[ni * 16] = oacc[mi][ni][j2];
    }
  #undef GLD
}

extern "C" void kernel_launch(void* const* d_in, const int* in_sizes, int n_in,
                              void* d_out, int out_size, void* d_ws, size_t ws_size,
                              hipStream_t stream) {
  const float* x      = (const float*)d_in[0];
  const float* W      = (const float*)d_in[1];
  const float* b      = (const float*)d_in[2];
  const float* Wg     = (const float*)d_in[3];
  const float* bg     = (const float*)d_in[4];
  const float* cached = (const float*)d_in[5];
  float* out = (float*)d_out;

  // ws layout: gate[N*E f32] | xb[N*H bf16] | wt[E*H*H bf16]  (~96.3 MB)
  char* ws = (char*)d_ws;
  float* gate = (float*)ws;
  unsigned short* xbuf = (unsigned short*)(ws + (size_t)NT * NE * 4);
  unsigned short* wtb  = (unsigned short*)(ws + (size_t)NT * NE * 4 + (size_t)NT * HD * 2);

  (void)hipFuncSetAttribute((const void*)moe_main,
                            hipFuncAttributeMaxDynamicSharedMemorySize, 147456);

  gate_kernel<<<NT / 4, 256, 0, stream>>>(x, Wg, bg, gate, xbuf);
  wtrans_kernel<<<dim3(HD / 64, HD / 64, NE), 256, 0, stream>>>(W, wtb);
  moe_main<<<dim3((NT / 128) * (HD / 256)), 512, 147456, stream>>>(xbuf, wtb, b, cached, gate, out);
}